// Round 3
// baseline (184.137 us; speedup 1.0000x reference)
//
#include <hip/hip_runtime.h>
#include <stdint.h>

typedef __attribute__((ext_vector_type(8))) short short8;
typedef __attribute__((ext_vector_type(4))) float f32x4;

#define K_DIM 4096
#define N_DIM 128
#define M_DIM 4096
#define NT 64            // K-steps of 64

__device__ __forceinline__ uint16_t f2bf(float f) {
    uint32_t u = __float_as_uint(f);
    return (uint16_t)((u + 0x7FFFu + ((u >> 16) & 1u)) >> 16);
}

__device__ __forceinline__ short8 cvt8(const float4 lo, const float4 hi) {
    short8 r;
    r[0] = (short)f2bf(lo.x); r[1] = (short)f2bf(lo.y);
    r[2] = (short)f2bf(lo.z); r[3] = (short)f2bf(lo.w);
    r[4] = (short)f2bf(hi.x); r[5] = (short)f2bf(hi.y);
    r[6] = (short)f2bf(hi.z); r[7] = (short)f2bf(hi.w);
    return r;
}

// ---- prep: W f32 -> bf16 (3 matrices of 128 x 4096) ----
__global__ __launch_bounds__(256) void prep_kernel(
    const float* __restrict__ W0, const float* __restrict__ W1,
    const float* __restrict__ W2, uint16_t* __restrict__ Wb)
{
    int gid = blockIdx.x * 256 + threadIdx.x;   // 0 .. 196607
    int g = gid >> 16;                          // 65536 threads per matrix
    int e = (gid & 65535) * 8;
    const float* W = (g == 0) ? W0 : (g == 1) ? W1 : W2;
    float4 lo = *(const float4*)(W + e);
    float4 hi = *(const float4*)(W + e + 4);
    *(short8*)(Wb + (size_t)g * (N_DIM * K_DIM) + e) = cvt8(lo, hi);
}

// ---- GEMM: z_g = x_g @ W_g^T, barrier-free / LDS-free ----
// grid = 768 (g = bid>>8, 16-row m-tile = bid&255), block = 256 thr = 4 waves.
// Wave wv owns cols [wv*32, wv*32+32): 2 MFMA col-fragments. B fragments are
// loaded DIRECTLY from global (W bf16 is 1 MB/matrix, L2-resident; per-lane
// fragment = 8 contiguous k of one W row, so lanes {i,i+16,i+32,i+48} jointly
// consume whole 64B lines). A loaded as float4 pairs, converted in-register.
// No __syncthreads anywhere: waves are independent; 3 blocks/CU = 12 waves/CU
// of TLP + 1-deep register prefetch hide HBM latency.
__global__ __launch_bounds__(256) void gemm3_kernel(
    const float* __restrict__ x0, const float* __restrict__ x1,
    const float* __restrict__ x2, const uint16_t* __restrict__ Wb,
    float* __restrict__ z)
{
    const int tid  = threadIdx.x;
    const int lane = tid & 63;
    const int wv   = tid >> 6;
    const int g    = blockIdx.x >> 8;
    const int mt   = blockIdx.x & 255;

    const float* x = (g == 0) ? x0 : (g == 1) ? x1 : x2;
    const uint16_t* Wg = Wb + (size_t)g * (N_DIM * K_DIM);
    float* zg = z + (size_t)g * (M_DIM * N_DIM);

    const int c16 = lane & 15;
    const int qg  = lane >> 4;
    const int rowbase = mt * 16;
    const int n0 = wv * 32;

    // A-frag source: lane (c16,qg) holds x[rowbase+c16][k0 + h*32 + qg*8 .. +7]
    const float* aptr = x + (size_t)(rowbase + c16) * K_DIM + qg * 8;
    // B-frag source: lane (c16,qg) holds W[n0 + nf*16 + c16][k0 + h*32 + qg*8 .. +7]
    const uint16_t* bptr = Wg + (size_t)(n0 + c16) * K_DIM + qg * 8;

    f32x4 acc[2];
    acc[0] = (f32x4)0.f;
    acc[1] = (f32x4)0.f;

    float4 a_cur[4], a_nxt[4];
    short8 b_cur[4], b_nxt[4];

    // tile 0: A = {h0:lo,hi, h1:lo,hi}; B = {h0 nf0, h0 nf1, h1 nf0, h1 nf1}
    a_cur[0] = *(const float4*)(aptr);
    a_cur[1] = *(const float4*)(aptr + 4);
    a_cur[2] = *(const float4*)(aptr + 32);
    a_cur[3] = *(const float4*)(aptr + 36);
    b_cur[0] = *(const short8*)(bptr);
    b_cur[1] = *(const short8*)(bptr + (size_t)16 * K_DIM);
    b_cur[2] = *(const short8*)(bptr + 32);
    b_cur[3] = *(const short8*)(bptr + (size_t)16 * K_DIM + 32);

    for (int kt = 0; kt < NT; ++kt) {
        if (kt + 1 < NT) {
            const int kn = (kt + 1) * 64;
            a_nxt[0] = *(const float4*)(aptr + kn);
            a_nxt[1] = *(const float4*)(aptr + kn + 4);
            a_nxt[2] = *(const float4*)(aptr + kn + 32);
            a_nxt[3] = *(const float4*)(aptr + kn + 36);
            b_nxt[0] = *(const short8*)(bptr + kn);
            b_nxt[1] = *(const short8*)(bptr + (size_t)16 * K_DIM + kn);
            b_nxt[2] = *(const short8*)(bptr + kn + 32);
            b_nxt[3] = *(const short8*)(bptr + (size_t)16 * K_DIM + kn + 32);
        }
        short8 af0 = cvt8(a_cur[0], a_cur[1]);
        acc[0] = __builtin_amdgcn_mfma_f32_16x16x32_bf16(af0, b_cur[0], acc[0], 0, 0, 0);
        acc[1] = __builtin_amdgcn_mfma_f32_16x16x32_bf16(af0, b_cur[1], acc[1], 0, 0, 0);
        short8 af1 = cvt8(a_cur[2], a_cur[3]);
        acc[0] = __builtin_amdgcn_mfma_f32_16x16x32_bf16(af1, b_cur[2], acc[0], 0, 0, 0);
        acc[1] = __builtin_amdgcn_mfma_f32_16x16x32_bf16(af1, b_cur[3], acc[1], 0, 0, 0);
#pragma unroll
        for (int i = 0; i < 4; ++i) { a_cur[i] = a_nxt[i]; b_cur[i] = b_nxt[i]; }
    }

    // C/D layout (m89-verified): col = lane&15, row = (lane>>4)*4 + reg
#pragma unroll
    for (int nf = 0; nf < 2; ++nf) {
#pragma unroll
        for (int r = 0; r < 4; ++r) {
            zg[(size_t)(rowbase + qg * 4 + r) * N_DIM + n0 + nf * 16 + c16] = acc[nf][r];
        }
    }
}

// ---- combine: aligned = (zc+zt+zl)/3 ; per-block loss partial sums ----
__global__ __launch_bounds__(256) void combine_kernel(
    const float* __restrict__ z, float* __restrict__ out,
    float* __restrict__ partials)
{
    const int tid = threadIdx.x;
    const size_t i = ((size_t)blockIdx.x * 256 + tid) * 4;
    const float4 a = *(const float4*)(z + i);
    const float4 b = *(const float4*)(z + (size_t)M_DIM * N_DIM + i);
    const float4 c = *(const float4*)(z + (size_t)2 * M_DIM * N_DIM + i);
    float4 al;
    al.x = (a.x + b.x + c.x) * (1.f / 3.f);
    al.y = (a.y + b.y + c.y) * (1.f / 3.f);
    al.z = (a.z + b.z + c.z) * (1.f / 3.f);
    al.w = (a.w + b.w + c.w) * (1.f / 3.f);
    *(float4*)(out + i) = al;

    float s = 0.f;
#define LOSS(u, v, w) { float d1 = (u)-(v), d2 = (u)-(w), d3 = (v)-(w); s += d1*d1 + d2*d2 + d3*d3; }
    LOSS(a.x, b.x, c.x) LOSS(a.y, b.y, c.y) LOSS(a.z, b.z, c.z) LOSS(a.w, b.w, c.w)
#undef LOSS
#pragma unroll
    for (int off = 32; off > 0; off >>= 1) s += __shfl_xor(s, off);
    __shared__ float wsum[4];
    if ((tid & 63) == 0) wsum[tid >> 6] = s;
    __syncthreads();
    if (tid == 0) partials[blockIdx.x] = wsum[0] + wsum[1] + wsum[2] + wsum[3];
}

__global__ __launch_bounds__(256) void finalize_kernel(
    const float* __restrict__ partials, float* __restrict__ out)
{
    const int tid = threadIdx.x;
    float s = partials[tid] + partials[tid + 256];
#pragma unroll
    for (int off = 32; off > 0; off >>= 1) s += __shfl_xor(s, off);
    __shared__ float wsum[4];
    if ((tid & 63) == 0) wsum[tid >> 6] = s;
    __syncthreads();
    if (tid == 0)
        out[(size_t)M_DIM * N_DIM] =
            (wsum[0] + wsum[1] + wsum[2] + wsum[3]) * (1.f / 12288.f) - 0.05f;
}

extern "C" void kernel_launch(void* const* d_in, const int* in_sizes, int n_in,
                              void* d_out, int out_size, void* d_ws, size_t ws_size,
                              hipStream_t stream)
{
    const float* x0 = (const float*)d_in[0];
    const float* x1 = (const float*)d_in[1];
    const float* x2 = (const float*)d_in[2];
    const float* W0 = (const float*)d_in[3];
    const float* W1 = (const float*)d_in[4];
    const float* W2 = (const float*)d_in[5];
    float* out = (float*)d_out;

    char* ws = (char*)d_ws;
    float*    zbuf     = (float*)ws;                                  // 6,291,456 B
    uint16_t* Wb       = (uint16_t*)(ws + 6291456);                   // 3,145,728 B
    float*    partials = (float*)(ws + 6291456 + 3145728);            // 2,048 B

    prep_kernel    <<<768, 256, 0, stream>>>(W0, W1, W2, Wb);
    gemm3_kernel   <<<768, 256, 0, stream>>>(x0, x1, x2, Wb, zbuf);
    combine_kernel <<<512, 256, 0, stream>>>(zbuf, out, partials);
    finalize_kernel<<<  1, 256, 0, stream>>>(partials, out);
}

// Round 4
// 52.517 us; speedup vs baseline: 3.5062x; 3.5062x over previous
//
#include <hip/hip_runtime.h>
#include <stdint.h>

typedef __attribute__((ext_vector_type(8))) short short8;
typedef __attribute__((ext_vector_type(4))) float f32x4;

#define K_DIM 4096
#define N_DIM 128
#define M_DIM 4096
#define MN ((size_t)M_DIM * N_DIM)

__device__ __forceinline__ uint16_t f2bf(float f) {
    uint32_t u = __float_as_uint(f);
    return (uint16_t)((u + 0x7FFFu + ((u >> 16) & 1u)) >> 16);
}

__device__ __forceinline__ short8 cvt8(const float4 lo, const float4 hi) {
    short8 r;
    r[0] = (short)f2bf(lo.x); r[1] = (short)f2bf(lo.y);
    r[2] = (short)f2bf(lo.z); r[3] = (short)f2bf(lo.w);
    r[4] = (short)f2bf(hi.x); r[5] = (short)f2bf(hi.y);
    r[6] = (short)f2bf(hi.z); r[7] = (short)f2bf(hi.w);
    return r;
}

// ---- prep: W f32 -> bf16 (3 matrices of 128 x 4096) ----
__global__ __launch_bounds__(256) void prep_kernel(
    const float* __restrict__ W0, const float* __restrict__ W1,
    const float* __restrict__ W2, uint16_t* __restrict__ Wb)
{
    int gid = blockIdx.x * 256 + threadIdx.x;   // 0 .. 196607
    int g = gid >> 16;                          // 65536 threads per matrix
    int e = (gid & 65535) * 8;
    const float* W = (g == 0) ? W0 : (g == 1) ? W1 : W2;
    float4 lo = *(const float4*)(W + e);
    float4 hi = *(const float4*)(W + e + 4);
    *(short8*)(Wb + (size_t)g * (N_DIM * K_DIM) + e) = cvt8(lo, hi);
}

// ---- GEMM with K-split: zpart[ks][g] += x_g[mtile] @ W_g[kchunk]^T ----
// R0's verified per-iteration structure (BM=64, BN=128, BK=64: 16 MFMA +
// 8 ds_read_b128 + 4 global_load_lds per wave per barrier, 0 bank conflicts),
// K-split NS ways so grid = 192*NS blocks -> 3 blocks/CU at NS=4 (12 waves/CU,
// independent barriers overlap per m114). XCD swizzle: 96 consecutive logical
// blocks per XCD => the 64 blocks sharing a (g,ks) B-chunk co-locate on one L2.
template<int NS>
__global__ __launch_bounds__(256) void gemm3_kernel(
    const float* __restrict__ x0, const float* __restrict__ x1,
    const float* __restrict__ x2, const uint16_t* __restrict__ Wb,
    float* __restrict__ zpart)
{
    __shared__ uint16_t lds[2][8192];   // 2 x 16 KiB: [col(128)][granule(8) of 8 bf16]

    const int tid  = threadIdx.x;
    const int lane = tid & 63;
    const int wv   = tid >> 6;

    const int per = (192 * NS) >> 3;                 // blocks per XCD
    const int lid = (blockIdx.x & 7) * per + (blockIdx.x >> 3);
    const int g   = lid / (NS * 64);
    const int rem = lid % (NS * 64);
    const int ks  = rem >> 6;
    const int mt  = rem & 63;
    const int k0  = ks * (K_DIM / NS);
    const int NT  = (K_DIM / NS) / 64;

    const float* x = (g == 0) ? x0 : (g == 1) ? x1 : x2;
    const uint16_t* Wg = Wb + (size_t)g * (N_DIM * K_DIM);
    float* zp = zpart + (size_t)(ks * 3 + g) * MN;

    const int c16 = lane & 15;
    const int qg  = lane >> 4;
    const int rowbase = mt * 64 + wv * 16;
    const float* aptr = x + (size_t)(rowbase + c16) * K_DIM + qg * 8 + k0;

    // staging source per call c: col = c*32 + (tid>>3), slot = tid&7, granule = slot ^ (col&7)
    const int t8 = tid >> 3, slot = tid & 7;
    const uint16_t* wsrc[4];
#pragma unroll
    for (int c = 0; c < 4; ++c) {
        int col = c * 32 + t8;
        wsrc[c] = Wg + (size_t)col * K_DIM + (slot ^ (col & 7)) * 8 + k0;
    }

    f32x4 acc[8];
#pragma unroll
    for (int nf = 0; nf < 8; ++nf) acc[nf] = (f32x4)0.f;

    auto stage = [&](int p, int kbase) {
#pragma unroll
        for (int c = 0; c < 4; ++c) {
            __builtin_amdgcn_global_load_lds(
                (const __attribute__((address_space(1))) uint32_t*)(wsrc[c] + kbase),
                (__attribute__((address_space(3))) uint32_t*)&lds[p][c * 2048 + wv * 512],
                16, 0, 0);
        }
    };

    stage(0, 0);
    float4 a_cur[4], a_nxt[4];
    a_cur[0] = *(const float4*)(aptr);
    a_cur[1] = *(const float4*)(aptr + 4);
    a_cur[2] = *(const float4*)(aptr + 32);
    a_cur[3] = *(const float4*)(aptr + 36);

    int p = 0;
    for (int kt = 0; kt < NT; ++kt) {
        const int kbase = kt * 64;
        __syncthreads();            // staging of buffer p (and A prefetch) complete
        if (kt + 1 < NT) {
            stage(p ^ 1, kbase + 64);
            const float* ap = aptr + kbase + 64;
            a_nxt[0] = *(const float4*)(ap);
            a_nxt[1] = *(const float4*)(ap + 4);
            a_nxt[2] = *(const float4*)(ap + 32);
            a_nxt[3] = *(const float4*)(ap + 36);
        }
#pragma unroll
        for (int h = 0; h < 2; ++h) {           // kk = 32*h
            short8 af = cvt8(a_cur[2 * h], a_cur[2 * h + 1]);
            const int boff = c16 * 64 + (((h * 4) + qg) ^ (lane & 7)) * 8;
#pragma unroll
            for (int nf = 0; nf < 8; ++nf) {
                short8 bf = *(const short8*)&lds[p][nf * 1024 + boff];
                acc[nf] = __builtin_amdgcn_mfma_f32_16x16x32_bf16(af, bf, acc[nf], 0, 0, 0);
            }
        }
#pragma unroll
        for (int i = 0; i < 4; ++i) a_cur[i] = a_nxt[i];
        p ^= 1;
    }

    // C/D layout (m89-verified): col = lane&15, row = (lane>>4)*4 + reg
#pragma unroll
    for (int nf = 0; nf < 8; ++nf) {
#pragma unroll
        for (int r = 0; r < 4; ++r) {
            zp[(size_t)(rowbase + qg * 4 + r) * N_DIM + nf * 16 + c16] = acc[nf][r];
        }
    }
}

// ---- combine: sum K-split partials, aligned = (zc+zt+zl)/3, loss partials ----
template<int NS>
__global__ __launch_bounds__(256) void combine_kernel(
    const float* __restrict__ zpart, float* __restrict__ out,
    float* __restrict__ partials)
{
    const int tid = threadIdx.x;
    const size_t i = ((size_t)blockIdx.x * 256 + tid) * 4;

    float4 zsum[3];
#pragma unroll
    for (int g = 0; g < 3; ++g) {
        float4 s = *(const float4*)(zpart + (size_t)g * MN + i);
#pragma unroll
        for (int ks = 1; ks < NS; ++ks) {
            const float4 v = *(const float4*)(zpart + (size_t)(ks * 3 + g) * MN + i);
            s.x += v.x; s.y += v.y; s.z += v.z; s.w += v.w;
        }
        zsum[g] = s;
    }
    const float4 a = zsum[0], b = zsum[1], c = zsum[2];
    float4 al;
    al.x = (a.x + b.x + c.x) * (1.f / 3.f);
    al.y = (a.y + b.y + c.y) * (1.f / 3.f);
    al.z = (a.z + b.z + c.z) * (1.f / 3.f);
    al.w = (a.w + b.w + c.w) * (1.f / 3.f);
    *(float4*)(out + i) = al;

    float s = 0.f;
#define LOSS(u, v, w) { float d1 = (u)-(v), d2 = (u)-(w), d3 = (v)-(w); s += d1*d1 + d2*d2 + d3*d3; }
    LOSS(a.x, b.x, c.x) LOSS(a.y, b.y, c.y) LOSS(a.z, b.z, c.z) LOSS(a.w, b.w, c.w)
#undef LOSS
#pragma unroll
    for (int off = 32; off > 0; off >>= 1) s += __shfl_xor(s, off);
    __shared__ float wsum[4];
    if ((tid & 63) == 0) wsum[tid >> 6] = s;
    __syncthreads();
    if (tid == 0) partials[blockIdx.x] = wsum[0] + wsum[1] + wsum[2] + wsum[3];
}

__global__ __launch_bounds__(256) void finalize_kernel(
    const float* __restrict__ partials, float* __restrict__ out)
{
    const int tid = threadIdx.x;
    float s = partials[tid] + partials[tid + 256];
#pragma unroll
    for (int off = 32; off > 0; off >>= 1) s += __shfl_xor(s, off);
    __shared__ float wsum[4];
    if ((tid & 63) == 0) wsum[tid >> 6] = s;
    __syncthreads();
    if (tid == 0)
        out[MN] = (wsum[0] + wsum[1] + wsum[2] + wsum[3]) * (1.f / 12288.f) - 0.05f;
}

extern "C" void kernel_launch(void* const* d_in, const int* in_sizes, int n_in,
                              void* d_out, int out_size, void* d_ws, size_t ws_size,
                              hipStream_t stream)
{
    const float* x0 = (const float*)d_in[0];
    const float* x1 = (const float*)d_in[1];
    const float* x2 = (const float*)d_in[2];
    const float* W0 = (const float*)d_in[3];
    const float* W1 = (const float*)d_in[4];
    const float* W2 = (const float*)d_in[5];
    float* out = (float*)d_out;

    const size_t zpart4_bytes = (size_t)4 * 3 * MN * sizeof(float);   // 25,165,824
    const size_t wb_bytes = (size_t)3 * N_DIM * K_DIM * sizeof(uint16_t); // 3,145,728
    const bool split4 = ws_size >= zpart4_bytes + wb_bytes + 2048;

    char* ws = (char*)d_ws;
    float*    zpart    = (float*)ws;
    size_t    zbytes   = split4 ? zpart4_bytes : (size_t)3 * MN * sizeof(float);
    uint16_t* Wb       = (uint16_t*)(ws + zbytes);
    float*    partials = (float*)(ws + zbytes + wb_bytes);

    prep_kernel<<<768, 256, 0, stream>>>(W0, W1, W2, Wb);
    if (split4) {
        gemm3_kernel<4><<<768, 256, 0, stream>>>(x0, x1, x2, Wb, zpart);
        combine_kernel<4><<<512, 256, 0, stream>>>(zpart, out, partials);
    } else {
        gemm3_kernel<1><<<192, 256, 0, stream>>>(x0, x1, x2, Wb, zpart);
        combine_kernel<1><<<512, 256, 0, stream>>>(zpart, out, partials);
    }
    finalize_kernel<<<1, 256, 0, stream>>>(partials, out);
}